// Round 6
// baseline (94.634 us; speedup 1.0000x reference)
//
#include <hip/hip_runtime.h>

// EmbedDNF: B=128, IN_F=256, HID=512, OUT=128, E=8 (fp32, e innermost)
//
// impl = 1 - w*(1-xnor) = A + x*Bv ; A = 1 - w*s ; Bv = 2*w*s - w
// H[b,h,e]   = prod_i (A[i,h,e] + x[b,i,e]*Bv[i,h,e])
// out[b,o,e] = 1 - prod_h (1 - dw[h,o,e]*H[b,h,e])
//
// Laws (R4-R16): (1) acc <= 32 VGPR; total VGPR <= the launch_bounds(256,4)
// cap of 128; (2) broadcast operands in LDS; (3) no device-scope fences;
// (4) >= 4 blocks/CU resident; (5) kernels are latency-bound (VALUBusy ~4%);
// (6) R15 LESSON: per-CU outstanding VMEM is HW-capped (~20-25 lines) —
// raising per-wave MLP 16x while halving waves REGRESSED (89->94). Stall
// time ~ traffic x latency / cap -> the lever is per-CU VMEM TRAFFIC.
// Ledger (R0-R15): dur 89.2 = fill ~43 (harness poison, untouchable,
// in-window) + s1 ~30 + s2 ~13 + comb2 ~3.
// This round (R16): stage1 b-tile 8 -> 16 per block (bg8, grid 1024),
// TWO b-half passes sharing one set of w/s-derived A/Bv registers ->
// w/s VMEM 134 MB -> 67 MB (amplification 16x -> 8x). acc stays 8 float4;
// ~110 VGPR, 32 KB LDS, 4 blocks/CU. stage2 / comb2 unchanged.
//
// ws: P1 [8][512][128][8] fp32 @ 0        (16 MB)  stage1 i-split partials
//     P2 [16][128][128][8] fp32 @ 4194304 (8 MB)   stage2 h-split partials

#define LD4(p) (*(const float4*)(p))

static __device__ __forceinline__ float4 f4mul(float4 a, float4 b) {
    return make_float4(a.x*b.x, a.y*b.y, a.z*b.z, a.w*b.w);
}
static __device__ __forceinline__ float4 f4fma(float4 a, float4 b, float4 c) {
    return make_float4(fmaf(a.x,b.x,c.x), fmaf(a.y,b.y,c.y),
                       fmaf(a.z,b.z,c.z), fmaf(a.w,b.w,c.w));
}
static __device__ __forceinline__ float4 f4nfma1(float4 d, float4 h) {  // 1-d*h
    return make_float4(fmaf(-d.x,h.x,1.0f), fmaf(-d.y,h.y,1.0f),
                       fmaf(-d.z,h.z,1.0f), fmaf(-d.w,h.w,1.0f));
}

// ---------------------------------------------------------------------------
// Stage 1 (R16). Grid 1024. Decode: bits [1:0]=hg-lo, [2]=ks-lo, [4:3]=hg-hi,
// [6:5]=ks-hi, [9:7]=bg8. XCD = (hg&3)|(ks&1)<<2 -> per-XCD hot cw/cs set
// 1 MB, 8x bg L2 reuse. Block 256 = 4 waves = 4 i-subchunks of 8.
// Lane = eh2 x hl32; per-pass thread tile 8b x 1h x 4e (acc = 32 VGPR).
// Structure: stage x[16b] (16 KB) -> 16-deep w/s register prefetch ->
// pass bh=0 (derive A/Bv in place, 8 b-FMAs/step) -> epilogue -> pass bh=1
// (reuse A/Bv from regs, zero VMEM) -> epilogue. LDS 32 KB: x [0,4096) +
// combine [4096,8192). ~110 VGPR -> 4 blocks/CU = 16 waves/CU.
// ---------------------------------------------------------------------------
__global__ __launch_bounds__(256, 4) void k_stage1(
    const float* __restrict__ in,   // [128][256][8]
    const float* __restrict__ cw,   // [256][512][8]
    const float* __restrict__ cs,   // [256][512][8]
    float* __restrict__ P1)         // ws: [8][512][128][8]
{
    __shared__ float lds[8192];              // 32 KB
    const int t    = threadIdx.x;
    const int lane = t & 63;
    const int kc   = t >> 6;                 // 0..3
    const int eh   = lane & 1;
    const int hl   = lane >> 1;              // 0..31
    const int bid  = blockIdx.x;
    const int hg   = (bid & 3) | (((bid >> 3) & 3) << 2);        // 0..15
    const int ks   = ((bid >> 2) & 1) | (((bid >> 5) & 3) << 1); // 0..7
    const int bg   = bid >> 7;                                   // 0..7
    const int b0   = bg * 16;
    const int h    = hg * 32 + hl;
    const int e0   = eh * 4;

    // stage x[b0:+16][ks*32:+32][0:8] -> lds[0,4096), layout [b][i][e]
    {
        float4* xs4 = (float4*)lds;
        #pragma unroll
        for (int k = 0; k < 4; ++k) {
            const int f4  = t + k * 256;     // 0..1023
            const int b   = f4 >> 6;         // 0..15
            const int col = f4 & 63;         // float4 within 256-float row
            xs4[f4] = LD4(in + (b0 + b) * 2048 + ks * 256 + col * 4);
        }
    }
    __syncthreads();

    const int i0 = ks * 32 + kc * 8;
    const float* pw = cw + i0 * 4096 + h * 8 + e0;
    const float* ps = cs + i0 * 4096 + h * 8 + e0;
    const float* xbase = lds + kc * 64 + e0;    // + (bh*8+b)*256 + ii*8 imm
    float* cmb = lds + 4096;                    // combine region (16 KB)

    // 16-deep register prefetch of w/s — loaded ONCE, serves both b-halves.
    float4 wv[8], sv[8];
    #pragma unroll
    for (int ii = 0; ii < 8; ++ii) {
        wv[ii] = LD4(pw); pw += 4096;
        sv[ii] = LD4(ps); ps += 4096;
    }

    float4 Av[8], Bvv[8];                    // derived in pass 0, reused pass 1
    float4 acc[8];

    #pragma unroll
    for (int bh = 0; bh < 2; ++bh) {
        #pragma unroll
        for (int b = 0; b < 8; ++b) acc[b] = make_float4(1.f, 1.f, 1.f, 1.f);

        #pragma unroll
        for (int ii = 0; ii < 8; ++ii) {
            if (bh == 0) {                   // compile-time: derive A/Bv, retire wv/sv
                const float4 p = f4mul(wv[ii], sv[ii]);
                Av[ii]  = make_float4(1.f - p.x, 1.f - p.y, 1.f - p.z, 1.f - p.w);
                Bvv[ii] = make_float4(fmaf(2.f, p.x, -wv[ii].x),
                                      fmaf(2.f, p.y, -wv[ii].y),
                                      fmaf(2.f, p.z, -wv[ii].z),
                                      fmaf(2.f, p.w, -wv[ii].w));
            }
            #pragma unroll
            for (int b = 0; b < 8; ++b) {
                const float4 xv = LD4(xbase + (bh * 8 + b) * 256 + ii * 8);
                acc[b] = f4mul(acc[b], f4fma(xv, Bvv[ii], Av[ii]));
            }
        }

        // epilogue for this b-half: combine 4 kc, write 8 b rows to P1
        #pragma unroll
        for (int phase = 0; phase < 2; ++phase) {
            __syncthreads();                 // protect prior combine reads / x stage
            #pragma unroll
            for (int j = 0; j < 4; ++j)
                *(float4*)&cmb[kc * 1024 + j * 256 + hl * 8 + e0] = acc[phase * 4 + j];
            __syncthreads();
            {   // combine 4 kc; thread t -> one float4 of the 1024-float tile
                const int o4 = t * 4;        // j*256 + hl2*8 + eq*4
                float4 m = LD4(&cmb[o4]);
                #pragma unroll
                for (int c = 1; c < 4; ++c) m = f4mul(m, LD4(&cmb[c * 1024 + o4]));
                const int j   = o4 >> 8;
                const int hl2 = (o4 >> 3) & 31;
                const int eq  = o4 & 7;      // 0 or 4
                *(float4*)(P1 + ks * 524288 + (hg * 32 + hl2) * 1024
                              + (b0 + bh * 8 + phase * 4 + j) * 8 + eq) = m;
            }
        }
    }
}

// ---------------------------------------------------------------------------
// Stage 2 (R11 structure, R13 remap — UNCHANGED). Grid 1024 = ks16 (low
// bits: XCD = ks&7 pins P1 h-slices + dw slice in L2) x og4 x bg16.
// Block 256 = 4 waves; lane = eh2 x ol32; thread tile 8b x 1o x 4e.
// ---------------------------------------------------------------------------
__global__ __launch_bounds__(256, 4) void k_stage2(
    const float* __restrict__ dw,   // [512][128][8]
    const float* __restrict__ P1,   // ws: [8][512][128][8]
    float* __restrict__ P2)         // ws: [16][128][128][8]
{
    __shared__ float lds[4096];              // 16 KB: H-tile [0,2048) then combine
    const int t    = threadIdx.x;
    const int lane = t & 63;
    const int kc   = t >> 6;                 // 0..3
    const int eh   = lane & 1;
    const int ol   = lane >> 1;              // 0..31
    const int ks   = blockIdx.x & 15;        // LOW bits: XCD = ks&7
    const int og   = (blockIdx.x >> 4) & 3;
    const int bg   = blockIdx.x >> 6;        // 0..15
    const int b0   = bg * 8;
    const int o    = og * 32 + ol;
    const int e0   = eh * 4;
    const int h0   = ks * 32;

    // H-tile: product of the 8 i-split partials, layout [hl][b][e]
    {
        float4* ht4 = (float4*)lds;
        #pragma unroll
        for (int k = 0; k < 2; ++k) {
            const int f4  = t + k * 256;     // 0..511
            const int hl  = f4 >> 4;
            const int rem = f4 & 15;         // b*2 + eq
            const float* q = P1 + (h0 + hl) * 1024 + b0 * 8 + rem * 4;
            float4 m = LD4(q);
            #pragma unroll
            for (int c = 1; c < 8; ++c) m = f4mul(m, LD4(q + c * 524288));
            ht4[f4] = m;
        }
    }
    __syncthreads();

    const float* pd = dw + (h0 + kc * 8) * 1024 + o * 8 + e0;
    const float* hbase = lds + kc * 512 + e0;   // + ii*64 + b*8 (immediates)

    float4 acc[8];
    #pragma unroll
    for (int b = 0; b < 8; ++b) acc[b] = make_float4(1.f, 1.f, 1.f, 1.f);

    #pragma unroll
    for (int ii = 0; ii < 8; ++ii) {
        const float4 dv = LD4(pd);
        pd += 1024;
        #pragma unroll
        for (int b = 0; b < 8; ++b) {
            const float4 hv = LD4(hbase + ii * 64 + b * 8);
            acc[b] = f4mul(acc[b], f4nfma1(dv, hv));
        }
    }

    __syncthreads();                         // H-tile dead; reuse lds
    // 2 phases of 4 b: partial[kc][j4][ol32][e8] = 1024 floats per kc
    #pragma unroll
    for (int phase = 0; phase < 2; ++phase) {
        if (phase) __syncthreads();
        #pragma unroll
        for (int j = 0; j < 4; ++j)
            *(float4*)&lds[kc * 1024 + j * 256 + ol * 8 + e0] = acc[phase * 4 + j];
        __syncthreads();
        {
            const int o4 = t * 4;            // j*256 + ol2*8 + eq*4
            float4 m = LD4(&lds[o4]);
            #pragma unroll
            for (int c = 1; c < 4; ++c) m = f4mul(m, LD4(&lds[c * 1024 + o4]));
            const int j   = o4 >> 8;
            const int ol2 = (o4 >> 3) & 31;
            const int eq  = o4 & 7;
            *(float4*)(P2 + ks * 131072 + (b0 + phase * 4 + j) * 1024
                          + (og * 32 + ol2) * 8 + eq) = m;
        }
    }
}

// ---------------------------------------------------------------------------
// Final: out = 1 - prod over the 16 h-split partials. 8 MB read, 0.5 MB write.
// 16 independent loads per thread -> deep MLP. UNCHANGED.
// ---------------------------------------------------------------------------
__global__ __launch_bounds__(256, 4) void k_comb2(
    const float* __restrict__ P2,   // ws: [16][128][128][8]
    float* __restrict__ out)        // [128][128][8]
{
    const int idx4 = blockIdx.x * 256 + threadIdx.x;   // 0..32767
    float4 m = LD4(P2 + idx4 * 4);
    #pragma unroll
    for (int c = 1; c < 16; ++c)
        m = f4mul(m, LD4(P2 + c * 131072 + idx4 * 4));
    const float4 r = make_float4(1.f - m.x, 1.f - m.y, 1.f - m.z, 1.f - m.w);
    *(float4*)(out + idx4 * 4) = r;
}

extern "C" void kernel_launch(void* const* d_in, const int* in_sizes, int n_in,
                              void* d_out, int out_size, void* d_ws, size_t ws_size,
                              hipStream_t stream)
{
    const float* in = (const float*)d_in[0];   // [128][256][8]
    const float* cw = (const float*)d_in[1];   // [256][512][8]
    const float* cs = (const float*)d_in[2];   // [256][512][8]
    const float* dw = (const float*)d_in[3];   // [512][128][8]
    float* outp = (float*)d_out;               // [128][128][8]
    float* P1   = (float*)d_ws;                // 16 MB
    float* P2   = (float*)d_ws + 4194304;      // 8 MB

    k_stage1<<<1024, 256, 0, stream>>>(in, cw, cs, P1);
    k_stage2<<<1024, 256, 0, stream>>>(dw, P1, P2);
    k_comb2<<<128, 256, 0, stream>>>(P2, outp);
}

// Round 7
// 91.125 us; speedup vs baseline: 1.0385x; 1.0385x over previous
//
#include <hip/hip_runtime.h>

// EmbedDNF: B=128, IN_F=256, HID=512, OUT=128, E=8 (fp32, e innermost)
//
// impl = 1 - w*(1-xnor) = A + x*Bv ; A = 1 - w*s ; Bv = 2*w*s - w
// H[b,h,e]   = prod_i (A[i,h,e] + x[b,i,e]*Bv[i,h,e])
// out[b,o,e] = 1 - prod_h (1 - dw[h,o,e]*H[b,h,e])
//
// Laws (R4-R17): (1) acc <= 32 VGPR; (2) broadcast operands in LDS;
// (3) no device-scope fences; (4) >= 4 blocks/CU; (5) latency-bound
// (VALUBusy ~4%); (6) R15+R16 LESSON (two independent confirmations):
// in-flight VMEM concurrency SCALES WITH WAVE COUNT — halving occupancy
// cancels any traffic/MLP gain and costs ~5 us of VALU overlap. Stage1
// changes MUST keep 32 waves/CU: <=64 VGPR, <=16 KB LDS, grid 2048.
// Ledger (R0-R16): best 89.2 (R14) = fill ~43 (harness poison, in-window,
// untouchable) + s1 ~30 + s2 ~13 + comb2 ~3.
// This round (R17): halve s1 w/s traffic AT CONSTANT occupancy.
// Thread tile 8b x 4e -> 16b x 2e (acc still 32 VGPR): each w/s value
// serves 16 b -> w/s VMEM 134 -> 67 MB. Block = 16h x 32i x 16b,
// grid 2048 = hg32 x ks8 x bg8, x-tile [16b][32i][8e] = 16 KB (combine
// reuses it). Same XCD pinning (1 MB hot set). P1/s2/comb2 unchanged.
//
// ws: P1 [8][512][128][8] fp32 @ 0        (16 MB)  stage1 i-split partials
//     P2 [16][128][128][8] fp32 @ 4194304 (8 MB)   stage2 h-split partials

#define LD4(p) (*(const float4*)(p))
#define LD2(p) (*(const float2*)(p))

static __device__ __forceinline__ float4 f4mul(float4 a, float4 b) {
    return make_float4(a.x*b.x, a.y*b.y, a.z*b.z, a.w*b.w);
}
static __device__ __forceinline__ float4 f4nfma1(float4 d, float4 h) {  // 1-d*h
    return make_float4(fmaf(-d.x,h.x,1.0f), fmaf(-d.y,h.y,1.0f),
                       fmaf(-d.z,h.z,1.0f), fmaf(-d.w,h.w,1.0f));
}

// ---------------------------------------------------------------------------
// Stage 1 (R17). Grid 2048. Decode: bits[1:0]=hg-lo, [2]=ks-lo, [4:3]=ks-hi,
// [7:5]=hg-hi, [10:8]=bg. XCD = (hg&3)|(ks&1)<<2 -> per-XCD hot cw/cs set
// 1 MB (128 h x 128 i x 2 arrays), all 8 bg-siblings same-XCD -> 8x L2 reuse.
// Block 256 = 4 waves (kc = i-sub of 8). Lane = eQ4 x hl16 (eQ low for
// coalescing); thread tile 16b x 1h x 2e (acc = 16 float2 = 32 VGPR).
// Step: 2 dwordx2 streaming VMEM (w,s; 512 B contiguous per wave-load) +
// 16 immediate-offset ds_read_b64 broadcasts + ~70 VALU. 8 steps.
// kc-combine: 2 phases of 8 b via 16 KB LDS (slot = kc*512 + b*64 + lane,
// 2-way-conflict-free). ~60 VGPR, 16 KB LDS -> 8 blocks/CU = 32 waves/CU.
// ---------------------------------------------------------------------------
__global__ __launch_bounds__(256, 4) void k_stage1(
    const float* __restrict__ in,   // [128][256][8]
    const float* __restrict__ cw,   // [256][512][8]
    const float* __restrict__ cs,   // [256][512][8]
    float* __restrict__ P1)         // ws: [8][512][128][8]
{
    __shared__ float lds[4096];              // 16 KB: x-tile, then combine
    const int t    = threadIdx.x;
    const int lane = t & 63;
    const int kc   = t >> 6;                 // 0..3
    const int eQ   = lane & 3;               // 0..3 (e-pair)
    const int hl   = lane >> 2;              // 0..15
    const int bid  = blockIdx.x;
    const int hg   = (bid & 3) | (((bid >> 5) & 7) << 2);        // 0..31
    const int ks   = ((bid >> 2) & 1) | (((bid >> 3) & 3) << 1); // 0..7
    const int bg   = bid >> 8;                                   // 0..7
    const int b0   = bg * 16;
    const int h    = hg * 16 + hl;
    const int e0   = eQ * 2;

    // stage x[b0:+16][ks*32:+32][0:8] -> lds, layout [b][i][e] (16 KB)
    {
        float4* xs4 = (float4*)lds;
        #pragma unroll
        for (int k = 0; k < 4; ++k) {
            const int f4  = t + k * 256;     // 0..1023
            const int b   = f4 >> 6;         // 0..15
            const int col = f4 & 63;         // float4 within 256-float row
            xs4[f4] = LD4(in + (b0 + b) * 2048 + ks * 256 + col * 4);
        }
    }
    __syncthreads();

    const int i0 = ks * 32 + kc * 8;
    const float* pw = cw + i0 * 4096 + h * 8 + e0;
    const float* ps = cs + i0 * 4096 + h * 8 + e0;
    const float* xb = lds + kc * 64 + e0;    // + b*256 + ii*8 (immediates)

    float2 acc[16];
    #pragma unroll
    for (int b = 0; b < 16; ++b) acc[b] = make_float2(1.f, 1.f);

    #pragma unroll
    for (int ii = 0; ii < 8; ++ii) {
        const float2 w2 = LD2(pw);
        const float2 s2 = LD2(ps);
        pw += 4096; ps += 4096;
        const float2 p  = make_float2(w2.x * s2.x, w2.y * s2.y);
        const float2 A  = make_float2(1.f - p.x, 1.f - p.y);
        const float2 Bv = make_float2(fmaf(2.f, p.x, -w2.x),
                                      fmaf(2.f, p.y, -w2.y));
        #pragma unroll
        for (int b = 0; b < 16; ++b) {
            const float2 xv = LD2(xb + b * 256 + ii * 8);
            acc[b].x *= fmaf(xv.x, Bv.x, A.x);
            acc[b].y *= fmaf(xv.y, Bv.y, A.y);
        }
    }

    // combine 4 kc partials, 2 phases of 8 b; slot = kc*512 + b*64 + lane
    float2* cmb = (float2*)lds;              // 2048 float2 = 16 KB
    #pragma unroll
    for (int phase = 0; phase < 2; ++phase) {
        __syncthreads();                     // x-tile dead / protect prior reads
        #pragma unroll
        for (int b = 0; b < 8; ++b)
            cmb[kc * 512 + b * 64 + lane] = acc[phase * 8 + b];
        __syncthreads();
        #pragma unroll
        for (int r = 0; r < 2; ++r) {
            const int s = t * 2 + r;         // 0..511 = b*64 + (hl*4+eQ)
            float2 m = cmb[s];
            #pragma unroll
            for (int c = 1; c < 4; ++c) {
                const float2 v = cmb[c * 512 + s];
                m.x *= v.x; m.y *= v.y;
            }
            const int b   = s >> 6;          // 0..7
            const int rem = s & 63;
            const int hs  = rem >> 2;        // 0..15
            const int eq  = rem & 3;         // 0..3
            *(float2*)(P1 + ks * 524288 + (hg * 16 + hs) * 1024
                          + (b0 + phase * 8 + b) * 8 + eq * 2) = m;
        }
    }
}

// ---------------------------------------------------------------------------
// Stage 2 (R11 structure, R13 remap — UNCHANGED). Grid 1024 = ks16 (low
// bits: XCD = ks&7 pins P1 h-slices + dw slice in L2) x og4 x bg16.
// Block 256 = 4 waves; lane = eh2 x ol32; thread tile 8b x 1o x 4e.
// ---------------------------------------------------------------------------
__global__ __launch_bounds__(256, 4) void k_stage2(
    const float* __restrict__ dw,   // [512][128][8]
    const float* __restrict__ P1,   // ws: [8][512][128][8]
    float* __restrict__ P2)         // ws: [16][128][128][8]
{
    __shared__ float lds[4096];              // 16 KB: H-tile [0,2048) then combine
    const int t    = threadIdx.x;
    const int lane = t & 63;
    const int kc   = t >> 6;                 // 0..3
    const int eh   = lane & 1;
    const int ol   = lane >> 1;              // 0..31
    const int ks   = blockIdx.x & 15;        // LOW bits: XCD = ks&7
    const int og   = (blockIdx.x >> 4) & 3;
    const int bg   = blockIdx.x >> 6;        // 0..15
    const int b0   = bg * 8;
    const int o    = og * 32 + ol;
    const int e0   = eh * 4;
    const int h0   = ks * 32;

    // H-tile: product of the 8 i-split partials, layout [hl][b][e]
    {
        float4* ht4 = (float4*)lds;
        #pragma unroll
        for (int k = 0; k < 2; ++k) {
            const int f4  = t + k * 256;     // 0..511
            const int hl  = f4 >> 4;
            const int rem = f4 & 15;         // b*2 + eq
            const float* q = P1 + (h0 + hl) * 1024 + b0 * 8 + rem * 4;
            float4 m = LD4(q);
            #pragma unroll
            for (int c = 1; c < 8; ++c) m = f4mul(m, LD4(q + c * 524288));
            ht4[f4] = m;
        }
    }
    __syncthreads();

    const float* pd = dw + (h0 + kc * 8) * 1024 + o * 8 + e0;
    const float* hbase = lds + kc * 512 + e0;   // + ii*64 + b*8 (immediates)

    float4 acc[8];
    #pragma unroll
    for (int b = 0; b < 8; ++b) acc[b] = make_float4(1.f, 1.f, 1.f, 1.f);

    #pragma unroll
    for (int ii = 0; ii < 8; ++ii) {
        const float4 dv = LD4(pd);
        pd += 1024;
        #pragma unroll
        for (int b = 0; b < 8; ++b) {
            const float4 hv = LD4(hbase + ii * 64 + b * 8);
            acc[b] = f4mul(acc[b], f4nfma1(dv, hv));
        }
    }

    __syncthreads();                         // H-tile dead; reuse lds
    // 2 phases of 4 b: partial[kc][j4][ol32][e8] = 1024 floats per kc
    #pragma unroll
    for (int phase = 0; phase < 2; ++phase) {
        if (phase) __syncthreads();
        #pragma unroll
        for (int j = 0; j < 4; ++j)
            *(float4*)&lds[kc * 1024 + j * 256 + ol * 8 + e0] = acc[phase * 4 + j];
        __syncthreads();
        {
            const int o4 = t * 4;            // j*256 + ol2*8 + eq*4
            float4 m = LD4(&lds[o4]);
            #pragma unroll
            for (int c = 1; c < 4; ++c) m = f4mul(m, LD4(&lds[c * 1024 + o4]));
            const int j   = o4 >> 8;
            const int ol2 = (o4 >> 3) & 31;
            const int eq  = o4 & 7;
            *(float4*)(P2 + ks * 131072 + (b0 + phase * 4 + j) * 1024
                          + (og * 32 + ol2) * 8 + eq) = m;
        }
    }
}

// ---------------------------------------------------------------------------
// Final: out = 1 - prod over the 16 h-split partials. 8 MB read, 0.5 MB write.
// 16 independent loads per thread -> deep MLP. UNCHANGED.
// ---------------------------------------------------------------------------
__global__ __launch_bounds__(256, 4) void k_comb2(
    const float* __restrict__ P2,   // ws: [16][128][128][8]
    float* __restrict__ out)        // [128][128][8]
{
    const int idx4 = blockIdx.x * 256 + threadIdx.x;   // 0..32767
    float4 m = LD4(P2 + idx4 * 4);
    #pragma unroll
    for (int c = 1; c < 16; ++c)
        m = f4mul(m, LD4(P2 + c * 131072 + idx4 * 4));
    const float4 r = make_float4(1.f - m.x, 1.f - m.y, 1.f - m.z, 1.f - m.w);
    *(float4*)(out + idx4 * 4) = r;
}

extern "C" void kernel_launch(void* const* d_in, const int* in_sizes, int n_in,
                              void* d_out, int out_size, void* d_ws, size_t ws_size,
                              hipStream_t stream)
{
    const float* in = (const float*)d_in[0];   // [128][256][8]
    const float* cw = (const float*)d_in[1];   // [256][512][8]
    const float* cs = (const float*)d_in[2];   // [256][512][8]
    const float* dw = (const float*)d_in[3];   // [512][128][8]
    float* outp = (float*)d_out;               // [128][128][8]
    float* P1   = (float*)d_ws;                // 16 MB
    float* P2   = (float*)d_ws + 4194304;      // 8 MB

    k_stage1<<<2048, 256, 0, stream>>>(in, cw, cs, P1);
    k_stage2<<<1024, 256, 0, stream>>>(dw, P1, P2);
    k_comb2<<<128, 256, 0, stream>>>(P2, outp);
}